// Round 9
// baseline (220.818 us; speedup 1.0000x reference)
//
#include <hip/hip_runtime.h>
#include <hip/hip_bf16.h>

// ---------------- problem constants (fixed by setup_inputs) ----------------
#define NUM_B   16
#define DIM     512
#define TT      1500
#define NROWS   (NUM_B * TT)              // 24000
#define NCODES  4096
#define ROW_TILES ((NROWS + 127) / 128)   // 188
#define NROWS_PAD (ROW_TILES * 128)       // 24064
#define NSLICE  8                         // partial cd slices (atomic decontention)
#define SHIFTC  30.0f                     // exp shift: exp(SHIFT-d), cancels in softmax
#define NBLKX   (NCODES / 128)            // 32 col tiles
#define TBLKS   (NUM_B * 47)              // 752 transpose blocks (47 t-tiles of 32)
#define CBLKS   (NCODES / 4)              // 1024 cb blocks
#define NZERO   (NROWS_PAD + NSLICE * NCODES)   // Sg + cdp
#define NZERO2  (NZERO + 2)               // + tot scalar + scan counter
#define RPB     188                       // rows per scan block (NROWS_PAD/128)
#define NSCAN   512                       // scan blocks (4 x 128)

typedef __bf16 bf16x8 __attribute__((ext_vector_type(8)));
typedef float  floatx4 __attribute__((ext_vector_type(4)));
typedef unsigned short ushortx8 __attribute__((ext_vector_type(8)));

// async global->LDS, 16B per lane; dest = wave-uniform base + lane*16
__device__ __forceinline__ void glds16(const void* g, void* l) {
    __builtin_amdgcn_global_load_lds(
        (__attribute__((address_space(1))) void*)(void*)g,
        (__attribute__((address_space(3))) void*)l, 16, 0, 0);
}

// ---------------- prep: transpose + z2 (register-accum) + cb + ws zeroing -------
__global__ __launch_bounds__(256) void k_prep(
    const float* __restrict__ sf, const float* __restrict__ cb,
    unsigned short* __restrict__ zbf, unsigned short* __restrict__ cbbf,
    float* __restrict__ z2, float* __restrict__ c2, float* __restrict__ zero0,
    float* __restrict__ outp) {
    int id = blockIdx.x, tid = threadIdx.x;
    if (id < TBLKS) {
        __shared__ float tile[32][257];
        int b = id / 47, t0 = (id % 47) * 32;
        int tl = tid & 31, dg = tid >> 5;       // phase 1: t lane, d group (8x32)
        int tr = tid >> 3, dgr = tid & 7;       // phase 2: 8 lanes per t-row
        int tg = t0 + tr;
        float ssq = 0.f;
        unsigned short* dst = zbf + (size_t)(b * TT + tg) * DIM;
#pragma unroll
        for (int half = 0; half < 2; ++half) {
            int dbase = half * 256;
            if (half) __syncthreads();          // drain phase-2 reads of prev half
            int t = t0 + tl;
            if (t < TT) {
                const float* src = sf + (size_t)(b * DIM + dbase + dg * 32) * TT + t;
#pragma unroll
                for (int k = 0; k < 32; ++k)
                    tile[tl][dg * 32 + k] = src[(size_t)k * TT];
            }
            __syncthreads();
            if (tg < TT) {
#pragma unroll
                for (int seg = 0; seg < 4; ++seg) {
                    int d0 = seg * 64 + dgr * 8;
                    unsigned int h[8];
#pragma unroll
                    for (int i2 = 0; i2 < 8; ++i2) {
                        __hip_bfloat16 hb = __float2bfloat16(tile[tr][d0 + i2]);
                        h[i2] = __builtin_bit_cast(unsigned short, hb);
                        float vb = __bfloat162float(hb);
                        ssq += vb * vb;
                    }
                    uint4 o;
                    o.x = h[0] | (h[1] << 16); o.y = h[2] | (h[3] << 16);
                    o.z = h[4] | (h[5] << 16); o.w = h[6] | (h[7] << 16);
                    *(uint4*)(dst + dbase + d0) = o;
                }
            }
        }
        // reduce over the 8 lanes sharing tr (lane bits 0..2)
        ssq += __shfl_xor(ssq, 1); ssq += __shfl_xor(ssq, 2); ssq += __shfl_xor(ssq, 4);
        if (dgr == 0 && tg < TT) z2[b * TT + tg] = ssq;
    } else {
        int ci = id - TBLKS;
        int gid = ci * 256 + tid;
        if (gid < NZERO2) zero0[gid] = 0.f;     // Sg + cdp + tot + cnt
        if (ci == 0 && tid == 0) outp[0] = 1.0f;
        int k = ci * 4 + (tid >> 6);
        int lane = tid & 63;
        const float4* src = (const float4*)(cb + (size_t)k * DIM + lane * 8);
        float4 a = src[0], b2 = src[1];
        float vals[8] = {a.x, a.y, a.z, a.w, b2.x, b2.y, b2.z, b2.w};
        float s = 0.f;
        unsigned int h[8];
#pragma unroll
        for (int i = 0; i < 8; ++i) {
            __hip_bfloat16 hb = __float2bfloat16(vals[i]);
            h[i] = __builtin_bit_cast(unsigned short, hb);
            float vb = __bfloat162float(hb);
            s += vb * vb;
        }
        uint4 o;
        o.x = h[0] | (h[1] << 16); o.y = h[2] | (h[3] << 16);
        o.z = h[4] | (h[5] << 16); o.w = h[6] | (h[7] << 16);
        *(uint4*)(cbbf + (size_t)k * DIM + lane * 8) = o;
#pragma unroll
        for (int off = 32; off >= 1; off >>= 1) s += __shfl_down(s, off);
        if (lane == 0) c2[k] = s;
    }
}

// ---------------- pass 1: GEMM + exp; accumulate S, store E bf16 ----------------
// Proven 128x128 2-phase structure; MFMA operands swapped (mfma(bv, av, acc) ->
// acc's 4 regs = 4 CONSECUTIVE codebook cols), packed 8B E-stores.
// Swapped C/D layout: row (n)  = wr + 16*i + (lane&15)
//                     col (k)  = wc + 16*j + (lane>>4)*4 + reg
__global__ __launch_bounds__(256, 2) void k_gemm1(
    const unsigned short* __restrict__ zbf, const unsigned short* __restrict__ cbbf,
    const float* __restrict__ z2, const float* __restrict__ c2,
    const int* __restrict__ lengths, const int* __restrict__ stride_p,
    float* __restrict__ Sg, unsigned short* __restrict__ Eg) {
    __shared__ unsigned short As[128 * 64];
    __shared__ unsigned short Bs[128 * 64];
    __shared__ float z2s[128], c2s[128];
    __shared__ unsigned char vldp[128];
    __shared__ int s_any;
    int tid = threadIdx.x;
    int r0 = blockIdx.y * 128, c0 = blockIdx.x * 128;
    if (tid == 0) s_any = 0;
    __syncthreads();
    if (tid < 128) {
        int n = r0 + tid;
        int valid = 0;
        if (n < NROWS) {
            int b = n / TT, t = n - b * TT;
            int stride = stride_p[0];
            int nv = lengths[b] / stride;
            if (nv > TT) nv = TT;
            valid = (t < nv);
        }
        if (valid) atomicOr(&s_any, 1);
        vldp[tid] = (unsigned char)valid;
        z2s[tid] = z2[r0 + tid];
        c2s[tid] = c2[c0 + tid];
    }
    __syncthreads();
    if (!s_any) return;   // fully-masked row tile: contributes nothing

    int wave = tid >> 6, lane = tid & 63;
    int l15 = lane & 15, l4 = lane >> 4;
    int wr = (wave >> 1) * 64, wc = (wave & 1) * 64;

    int srow = lane >> 3;
    int scg = (lane & 7) ^ srow;
    const unsigned short* ag = zbf + (size_t)(r0 + wave * 32 + srow) * DIM + scg * 8;
    const unsigned short* bg = cbbf + (size_t)(c0 + wave * 32 + srow) * DIM + scg * 8;
    unsigned short* al = As + (wave * 32) * 64;
    unsigned short* bl = Bs + (wave * 32) * 64;

    floatx4 acc[4][4];
    const floatx4 zero = {0.f, 0.f, 0.f, 0.f};
#pragma unroll
    for (int i = 0; i < 4; ++i)
#pragma unroll
        for (int j = 0; j < 4; ++j) acc[i][j] = zero;

    int sw = l15 & 7;

    for (int kc = 0; kc < 8; ++kc) {
#pragma unroll
        for (int q = 0; q < 4; ++q) {
            glds16(ag + (size_t)q * 8 * DIM + kc * 64, al + q * 8 * 64);
            glds16(bg + (size_t)q * 8 * DIM + kc * 64, bl + q * 8 * 64);
        }
        __syncthreads();
#pragma unroll
        for (int ks = 0; ks < 64; ks += 32) {
            int g = (ks >> 3) + l4;
            int pcg = g ^ sw;
            bf16x8 av[4], bv[4];
#pragma unroll
            for (int i = 0; i < 4; ++i)
                av[i] = __builtin_bit_cast(bf16x8,
                    *(const ushortx8*)&As[(wr + 16 * i + l15) * 64 + pcg * 8]);
#pragma unroll
            for (int j = 0; j < 4; ++j)
                bv[j] = __builtin_bit_cast(bf16x8,
                    *(const ushortx8*)&Bs[(wc + 16 * j + l15) * 64 + pcg * 8]);
#pragma unroll
            for (int i = 0; i < 4; ++i)
#pragma unroll
                for (int j = 0; j < 4; ++j)
                    acc[i][j] = __builtin_amdgcn_mfma_f32_16x16x32_bf16(bv[j], av[i], acc[i][j], 0, 0, 0);
        }
        __syncthreads();
    }

    // epilogue: e = exp(SHIFT - sqrt(z2+c2-2*dot)); S += row-sum; E[n][k] packed 8B
    float c2r[4][4];
#pragma unroll
    for (int j = 0; j < 4; ++j)
#pragma unroll
        for (int r = 0; r < 4; ++r)
            c2r[j][r] = c2s[wc + 16 * j + 4 * l4 + r];

#pragma unroll
    for (int i = 0; i < 4; ++i) {
        int rl = wr + 16 * i + l15;
        bool rv = vldp[rl] != 0;
        float z2v = z2s[rl];
        float s = 0.f;
        unsigned short* Ep = Eg + (size_t)(r0 + rl) * NCODES + c0 + wc + l4 * 4;
#pragma unroll
        for (int j = 0; j < 4; ++j) {
            float e[4];
#pragma unroll
            for (int r = 0; r < 4; ++r) {
                float d2 = z2v + c2r[j][r] - 2.0f * acc[i][j][r];
                float d = sqrtf(fmaxf(d2, 1e-12f));
                e[r] = __expf(SHIFTC - d);
                s += e[r];
            }
            if (rv) {
                unsigned h0 = __builtin_bit_cast(unsigned short, __float2bfloat16(e[0]));
                unsigned h1 = __builtin_bit_cast(unsigned short, __float2bfloat16(e[1]));
                unsigned h2 = __builtin_bit_cast(unsigned short, __float2bfloat16(e[2]));
                unsigned h3 = __builtin_bit_cast(unsigned short, __float2bfloat16(e[3]));
                uint2 o;
                o.x = h0 | (h1 << 16);
                o.y = h2 | (h3 << 16);
                *(uint2*)(Ep + 16 * j) = o;
            }
        }
        s += __shfl_xor(s, 16); s += __shfl_xor(s, 32);
        if (l4 == 0 && rv) atomicAdd(&Sg[r0 + rl], s);
    }
}

// ---------------- pass 2: scan + FUSED finalize (last-block finisher) -----------
// Grid (4, 128): 512 blocks = exactly 2/CU. Block (x,y) owns cols x*1024+[0,1024)
// and rows {y + 128*j, j<188} (interleaved -> balanced valid counts). cdp is
// written ONLY by device-scope atomics, so the last-block finisher needs no
// per-block L2 writeback (unlike R6's normal-store fusion): fence orders the
// atomics vs the counter; finisher reduces 8 slices + computes entropy -> out.
// Saves the k_red + k_ent launches and their inter-dispatch gaps.
__global__ __launch_bounds__(256) void k_scan(
    const unsigned short* __restrict__ Eg, const float* __restrict__ Sg,
    const int* __restrict__ lengths, const int* __restrict__ stride_p,
    float* __restrict__ cdp, int* __restrict__ cnt, float* __restrict__ out) {
    __shared__ float rs2[RPB];
    __shared__ unsigned char vrows[RPB];
    __shared__ int wtot[4];
    __shared__ int s_old;
    __shared__ float redw[4];
    int tid = threadIdx.x;
    int y0 = blockIdx.y;                    // 0..127
    int lane = tid & 63, wv = tid >> 6;

    int valid = 0;
    float inv = 0.f;
    if (tid < RPB) {
        int n = y0 + 128 * tid;
        if (n < NROWS) {
            int b = n / TT, t = n - b * TT;
            int nv = lengths[b] / stride_p[0];
            if (nv > TT) nv = TT;
            if (t < nv) { valid = 1; inv = 1.0f / Sg[n]; }
        }
    }
    unsigned long long mask = __ballot(valid);
    if (lane == 0) wtot[wv] = __popcll(mask);
    __syncthreads();
    int base = 0;
#pragma unroll
    for (int w = 0; w < 4; ++w) if (w < wv) base += wtot[w];
    if (valid) {
        int pos = base + __popcll(mask & ((1ull << lane) - 1ull));
        vrows[pos] = (unsigned char)tid;    // stores j (0..187)
        rs2[pos] = inv;
    }
    __syncthreads();
    int m = wtot[0] + wtot[1] + wtot[2] + wtot[3];

    if (m != 0) {
        int col0 = blockIdx.x * 1024 + tid * 4;
        const unsigned short* base_e = Eg + col0;
        float acc[4] = {0.f, 0.f, 0.f, 0.f};

#define ACC4(V, RN) do { \
    unsigned int _u[2] = {(V).x, (V).y}; \
    _Pragma("unroll") \
    for (int q = 0; q < 2; ++q) { \
        acc[2 * q]     += (RN) * __builtin_bit_cast(float, _u[q] << 16); \
        acc[2 * q + 1] += (RN) * __builtin_bit_cast(float, _u[q] & 0xffff0000u); \
    } \
} while (0)

#define ROWP(I) (base_e + (size_t)(y0 + 128 * (int)vrows[I]) * NCODES)
        int i = 0;
        for (; i + 8 <= m; i += 8) {
            uint2 v0 = *(const uint2*)ROWP(i);
            uint2 v1 = *(const uint2*)ROWP(i + 1);
            uint2 v2 = *(const uint2*)ROWP(i + 2);
            uint2 v3 = *(const uint2*)ROWP(i + 3);
            uint2 v4 = *(const uint2*)ROWP(i + 4);
            uint2 v5 = *(const uint2*)ROWP(i + 5);
            uint2 v6 = *(const uint2*)ROWP(i + 6);
            uint2 v7 = *(const uint2*)ROWP(i + 7);
            ACC4(v0, rs2[i]);     ACC4(v1, rs2[i + 1]);
            ACC4(v2, rs2[i + 2]); ACC4(v3, rs2[i + 3]);
            ACC4(v4, rs2[i + 4]); ACC4(v5, rs2[i + 5]);
            ACC4(v6, rs2[i + 6]); ACC4(v7, rs2[i + 7]);
        }
        for (; i < m; ++i) {
            uint2 v = *(const uint2*)ROWP(i);
            ACC4(v, rs2[i]);
        }
#undef ROWP
#undef ACC4

        float* outp = cdp + (size_t)(blockIdx.y & (NSLICE - 1)) * NCODES;
#pragma unroll
        for (int t = 0; t < 4; ++t) atomicAdd(&outp[col0 + t], acc[t]);
    }

    // ---- completion counter: ALL 512 blocks increment (incl. m==0) ------------
    __syncthreads();
    if (tid == 0) {
        __threadfence();                    // order cdp atomics before counter
        s_old = atomicAdd(cnt, 1);
    }
    __syncthreads();
    if (s_old != NSCAN - 1) return;

    // ---- finisher (one block): slice-reduce + entropy -------------------------
    __threadfence();                        // acquire
    float v16[16];
    {
        const float4* p0 = (const float4*)(cdp + (size_t)tid * 16);
#pragma unroll
        for (int q = 0; q < 4; ++q) {
            float4 v = p0[q];
            v16[4 * q] = v.x; v16[4 * q + 1] = v.y;
            v16[4 * q + 2] = v.z; v16[4 * q + 3] = v.w;
        }
    }
#pragma unroll
    for (int s = 1; s < NSLICE; ++s) {
        const float4* p = (const float4*)(cdp + (size_t)s * NCODES + (size_t)tid * 16);
#pragma unroll
        for (int q = 0; q < 4; ++q) {
            float4 v = p[q];
            v16[4 * q] += v.x; v16[4 * q + 1] += v.y;
            v16[4 * q + 2] += v.z; v16[4 * q + 3] += v.w;
        }
    }
    float t = 0.f;
#pragma unroll
    for (int q = 0; q < 16; ++q) t += v16[q];
#pragma unroll
    for (int off = 32; off >= 1; off >>= 1) t += __shfl_down(t, off);
    if (lane == 0) redw[wv] = t;
    __syncthreads();
    float tot = redw[0] + redw[1] + redw[2] + redw[3];
    float invt = 1.0f / (tot + 1e-8f);
    float e = 0.f;
#pragma unroll
    for (int q = 0; q < 16; ++q) {
        float p = v16[q] * invt;
        e += p * __logf(p + 1e-8f);
    }
#pragma unroll
    for (int off = 32; off >= 1; off >>= 1) e += __shfl_down(e, off);
    if (lane == 0) redw[wv] = e;
    __syncthreads();
    if (tid == 0) {
        float ee = redw[0] + redw[1] + redw[2] + redw[3];
        out[0] = 1.0f + ee / __logf((float)NCODES);
    }
}

// ---------------- fallback (small ws): two-pass GEMM (writes cdp slice 0) -------
template <int PASS>
__global__ __launch_bounds__(256, 2) void k_gemm(
    const unsigned short* __restrict__ zbf, const unsigned short* __restrict__ cbbf,
    const float* __restrict__ z2, const float* __restrict__ c2,
    const int* __restrict__ lengths, const int* __restrict__ stride_p,
    float* __restrict__ Sg, float* __restrict__ cd) {
    __shared__ unsigned short Asf[128 * 64];
    __shared__ unsigned short Bsf[128 * 64];
    __shared__ float z2s[128], c2s[128], rs[128];
    __shared__ int s_any;
    int tid = threadIdx.x;
    int r0 = blockIdx.y * 128, c0 = blockIdx.x * 128;
    if (tid == 0) s_any = 0;
    __syncthreads();
    if (tid < 128) {
        int n = r0 + tid;
        int valid = 0;
        if (n < NROWS) {
            int b = n / TT, t = n - b * TT;
            int stride = stride_p[0];
            int nv = lengths[b] / stride;
            if (nv > TT) nv = TT;
            valid = (t < nv);
        }
        if (valid) atomicOr(&s_any, 1);
        z2s[tid] = z2[r0 + tid];
        c2s[tid] = c2[c0 + tid];
        if (PASS == 2) rs[tid] = valid ? (1.0f / Sg[r0 + tid]) : 0.0f;
    }
    __syncthreads();
    if (!s_any) return;

    int wave = tid >> 6, lane = tid & 63;
    int l15 = lane & 15, l4 = lane >> 4;
    int wr = (wave >> 1) * 64, wc = (wave & 1) * 64;
    int srow = lane >> 3;
    int scg = (lane & 7) ^ srow;
    const unsigned short* ag = zbf + (size_t)(r0 + wave * 32 + srow) * DIM + scg * 8;
    const unsigned short* bg = cbbf + (size_t)(c0 + wave * 32 + srow) * DIM + scg * 8;
    unsigned short* al = Asf + (wave * 32) * 64;
    unsigned short* bl = Bsf + (wave * 32) * 64;

    floatx4 acc[4][4];
    const floatx4 zero = {0.f, 0.f, 0.f, 0.f};
#pragma unroll
    for (int i = 0; i < 4; ++i)
#pragma unroll
        for (int j = 0; j < 4; ++j) acc[i][j] = zero;
    int sw = l15 & 7;
    for (int kc = 0; kc < 8; ++kc) {
#pragma unroll
        for (int q = 0; q < 4; ++q) {
            glds16(ag + (size_t)q * 8 * DIM + kc * 64, al + q * 8 * 64);
            glds16(bg + (size_t)q * 8 * DIM + kc * 64, bl + q * 8 * 64);
        }
        __syncthreads();
#pragma unroll
        for (int ks = 0; ks < 64; ks += 32) {
            int g = (ks >> 3) + l4;
            int pcg = g ^ sw;
            bf16x8 av[4], bvv[4];
#pragma unroll
            for (int i = 0; i < 4; ++i)
                av[i] = __builtin_bit_cast(bf16x8, *(const ushortx8*)&Asf[(wr + 16 * i + l15) * 64 + pcg * 8]);
#pragma unroll
            for (int j = 0; j < 4; ++j)
                bvv[j] = __builtin_bit_cast(bf16x8, *(const ushortx8*)&Bsf[(wc + 16 * j + l15) * 64 + pcg * 8]);
#pragma unroll
            for (int i = 0; i < 4; ++i)
#pragma unroll
                for (int j = 0; j < 4; ++j)
                    acc[i][j] = __builtin_amdgcn_mfma_f32_16x16x32_bf16(av[i], bvv[j], acc[i][j], 0, 0, 0);
        }
        __syncthreads();
    }
    if (PASS == 1) {
#pragma unroll
        for (int i = 0; i < 4; ++i) {
#pragma unroll
            for (int r = 0; r < 4; ++r) {
                int rl = wr + 16 * i + 4 * l4 + r;
                float z2v = z2s[rl];
                float s = 0.f;
#pragma unroll
                for (int j = 0; j < 4; ++j) {
                    int cl = wc + 16 * j + l15;
                    float d2 = z2v + c2s[cl] - 2.0f * acc[i][j][r];
                    float d = sqrtf(fmaxf(d2, 1e-12f));
                    s += __expf(SHIFTC - d);
                }
                s += __shfl_xor(s, 1); s += __shfl_xor(s, 2);
                s += __shfl_xor(s, 4); s += __shfl_xor(s, 8);
                if (l15 == 0) atomicAdd(&Sg[r0 + rl], s);
            }
        }
    } else {
#pragma unroll
        for (int j = 0; j < 4; ++j) {
            int cl = wc + 16 * j + l15;
            float c2v = c2s[cl];
            float cs = 0.f;
#pragma unroll
            for (int i = 0; i < 4; ++i) {
#pragma unroll
                for (int r = 0; r < 4; ++r) {
                    int rl = wr + 16 * i + 4 * l4 + r;
                    float d2 = z2s[rl] + c2v - 2.0f * acc[i][j][r];
                    float d = sqrtf(fmaxf(d2, 1e-12f));
                    cs += __expf(SHIFTC - d) * rs[rl];
                }
            }
            cs += __shfl_xor(cs, 16); cs += __shfl_xor(cs, 32);
            if (l4 == 0) atomicAdd(&cd[c0 + cl], cs);
        }
    }
}

// ---------------- finalize (fallback path only) ---------------------------------
__global__ __launch_bounds__(256) void k_red(float* __restrict__ cdp,
                                             float* __restrict__ tot) {
    int k = blockIdx.x * 256 + threadIdx.x;
    float v = 0.f;
#pragma unroll
    for (int s = 0; s < NSLICE; ++s) v += cdp[(size_t)s * NCODES + k];
    cdp[k] = v;
    float t = v;
#pragma unroll
    for (int off = 32; off >= 1; off >>= 1) t += __shfl_down(t, off);
    if ((threadIdx.x & 63) == 0) atomicAdd(tot, t);
}

__global__ __launch_bounds__(256) void k_ent(const float* __restrict__ cdp,
                                             const float* __restrict__ tot,
                                             float* __restrict__ out) {
    int k = blockIdx.x * 256 + threadIdx.x;
    float inv = 1.0f / (tot[0] + 1e-8f);
    float p = cdp[k] * inv;
    float e = p * __logf(p + 1e-8f);
#pragma unroll
    for (int off = 32; off >= 1; off >>= 1) e += __shfl_down(e, off);
    if ((threadIdx.x & 63) == 0)
        atomicAdd(out, e * (1.0f / __logf((float)NCODES)));
}

// ---------------- launcher ----------------
extern "C" void kernel_launch(void* const* d_in, const int* in_sizes, int n_in,
                              void* d_out, int out_size, void* d_ws, size_t ws_size,
                              hipStream_t stream) {
    const float* sf = (const float*)d_in[0];
    const float* cb = (const float*)d_in[1];
    const int* lengths = (const int*)d_in[2];
    const int* stride_p = (const int*)d_in[3];

    float* wsf = (float*)d_ws;
    float* Sg = wsf;                                     // NROWS_PAD
    float* cdp = Sg + NROWS_PAD;                         // NSLICE*NCODES
    float* tot = wsf + NZERO;                            // 1 scalar (fallback)
    int* cnt = (int*)(wsf + NZERO + 1);                  // scan completion counter
    const size_t OFF_Z2 = NZERO2;
    const size_t OFF_C2 = OFF_Z2 + NROWS_PAD;
    const size_t OFF_ZB = (OFF_C2 + NCODES + 3) & ~(size_t)3;  // 16B-align bf16 region
    float* z2 = wsf + OFF_Z2;
    float* c2 = wsf + OFF_C2;
    unsigned short* zbf = (unsigned short*)(wsf + OFF_ZB);     // NROWS_PAD*DIM bf16
    unsigned short* cbbf = zbf + (size_t)NROWS_PAD * DIM;      // NCODES*DIM bf16
    unsigned short* Eg = cbbf + (size_t)NCODES * DIM;          // NROWS_PAD*NCODES bf16

    size_t need = OFF_ZB * 4
                + ((size_t)NROWS_PAD * DIM + (size_t)NCODES * DIM
                 + (size_t)NROWS_PAD * NCODES) * 2;

    k_prep<<<dim3(TBLKS + CBLKS), 256, 0, stream>>>(
        sf, cb, zbf, cbbf, z2, c2, Sg, (float*)d_out);
    if (ws_size >= need) {
        k_gemm1<<<dim3(NBLKX, ROW_TILES), 256, 0, stream>>>(
            zbf, cbbf, z2, c2, lengths, stride_p, Sg, Eg);
        k_scan<<<dim3(4, 128), 256, 0, stream>>>(
            Eg, Sg, lengths, stride_p, cdp, cnt, (float*)d_out);
    } else {
        k_gemm<1><<<dim3(NBLKX, ROW_TILES), 256, 0, stream>>>(zbf, cbbf, z2, c2, lengths, stride_p, Sg, cdp);
        k_gemm<2><<<dim3(NBLKX, ROW_TILES), 256, 0, stream>>>(zbf, cbbf, z2, c2, lengths, stride_p, Sg, cdp);
        k_red<<<dim3(NCODES / 256), 256, 0, stream>>>(cdp, tot);
        k_ent<<<dim3(NCODES / 256), 256, 0, stream>>>(cdp, tot, (float*)d_out);
    }
}

// Round 10
// 204.035 us; speedup vs baseline: 1.0823x; 1.0823x over previous
//
#include <hip/hip_runtime.h>
#include <hip/hip_bf16.h>

// ---------------- problem constants (fixed by setup_inputs) ----------------
#define NUM_B   16
#define DIM     512
#define TT      1500
#define NROWS   (NUM_B * TT)              // 24000
#define NCODES  4096
#define ROW_TILES ((NROWS + 127) / 128)   // 188
#define NROWS_PAD (ROW_TILES * 128)       // 24064
#define NSLICE  8                         // partial cd slices (atomic decontention)
#define SHIFTC  30.0f                     // exp shift: exp(SHIFT-d), cancels in softmax
#define NBLKX   (NCODES / 128)            // 32 col tiles
#define TBLKS   (NUM_B * 47)              // 752 transpose blocks (47 t-tiles of 32)
#define CBLKS   (NCODES / 4)              // 1024 cb blocks
#define NZERO   (NROWS_PAD + NSLICE * NCODES)   // Sg + cdp
#define NZERO2  (NZERO + 1)               // + tot scalar
#define RPB     188                       // max rows per scan block (NROWS_PAD/128)

typedef __bf16 bf16x8 __attribute__((ext_vector_type(8)));
typedef float  floatx4 __attribute__((ext_vector_type(4)));
typedef unsigned short ushortx8 __attribute__((ext_vector_type(8)));

// async global->LDS, 16B per lane; dest = wave-uniform base + lane*16
__device__ __forceinline__ void glds16(const void* g, void* l) {
    __builtin_amdgcn_global_load_lds(
        (__attribute__((address_space(1))) void*)(void*)g,
        (__attribute__((address_space(3))) void*)l, 16, 0, 0);
}

// valid-row count per batch + exclusive prefix (uniform, 16 scalar reads)
__device__ __forceinline__ void row_prefix(const int* __restrict__ lengths,
                                           int stride, int b,
                                           int* off_out, int* nv_out, int* tot_out) {
    int off = 0, nvb = 0, tot = 0;
#pragma unroll
    for (int bb = 0; bb < NUM_B; ++bb) {
        int nv = lengths[bb] / stride;
        if (nv > TT) nv = TT;
        if (bb < b) off += nv;
        if (bb == b) nvb = nv;
        tot += nv;
    }
    *off_out = off; *nv_out = nvb; *tot_out = tot;
}

// ---------------- prep: COMPACTED transpose + z2 + cb + ws zeroing --------------
// Valid rows (t < nv_b) are written to zbf/z2 at compact index off_b + t.
// Transpose blocks whose entire 32-row t-tile is invalid exit before loading
// (~halves transpose traffic for random lengths). Invalid rows never exist in
// the compact arrays; downstream validity is simply n < Ntot.
__global__ __launch_bounds__(256) void k_prep(
    const float* __restrict__ sf, const float* __restrict__ cb,
    const int* __restrict__ lengths, const int* __restrict__ stride_p,
    unsigned short* __restrict__ zbf, unsigned short* __restrict__ cbbf,
    float* __restrict__ z2, float* __restrict__ c2, float* __restrict__ zero0,
    float* __restrict__ outp) {
    int id = blockIdx.x, tid = threadIdx.x;
    if (id < TBLKS) {
        int b = id / 47, t0 = (id % 47) * 32;
        int off, nvb, tot;
        row_prefix(lengths, stride_p[0], b, &off, &nvb, &tot);
        if (t0 >= nvb) return;              // fully-invalid t-tile: nothing to emit

        __shared__ float tile[32][257];
        int tl = tid & 31, dg = tid >> 5;       // phase 1: t lane, d group (8x32)
        int tr = tid >> 3, dgr = tid & 7;       // phase 2: 8 lanes per t-row
        int tg = t0 + tr;
        float ssq = 0.f;
        unsigned short* dst = zbf + (size_t)(off + tg) * DIM;
#pragma unroll
        for (int half = 0; half < 2; ++half) {
            int dbase = half * 256;
            if (half) __syncthreads();          // drain phase-2 reads of prev half
            int t = t0 + tl;
            if (t < TT) {
                const float* src = sf + (size_t)(b * DIM + dbase + dg * 32) * TT + t;
#pragma unroll
                for (int k = 0; k < 32; ++k)
                    tile[tl][dg * 32 + k] = src[(size_t)k * TT];
            }
            __syncthreads();
            if (tg < nvb) {
#pragma unroll
                for (int seg = 0; seg < 4; ++seg) {
                    int d0 = seg * 64 + dgr * 8;
                    unsigned int h[8];
#pragma unroll
                    for (int i2 = 0; i2 < 8; ++i2) {
                        __hip_bfloat16 hb = __float2bfloat16(tile[tr][d0 + i2]);
                        h[i2] = __builtin_bit_cast(unsigned short, hb);
                        float vb = __bfloat162float(hb);
                        ssq += vb * vb;
                    }
                    uint4 o;
                    o.x = h[0] | (h[1] << 16); o.y = h[2] | (h[3] << 16);
                    o.z = h[4] | (h[5] << 16); o.w = h[6] | (h[7] << 16);
                    *(uint4*)(dst + dbase + d0) = o;
                }
            }
        }
        // reduce over the 8 lanes sharing tr (lane bits 0..2)
        ssq += __shfl_xor(ssq, 1); ssq += __shfl_xor(ssq, 2); ssq += __shfl_xor(ssq, 4);
        if (dgr == 0 && tg < nvb) z2[off + tg] = ssq;
    } else {
        int ci = id - TBLKS;
        int gid = ci * 256 + tid;
        if (gid < NZERO2) zero0[gid] = 0.f;     // Sg + cdp + tot
        if (ci == 0 && tid == 0) outp[0] = 1.0f;
        int k = ci * 4 + (tid >> 6);
        int lane = tid & 63;
        const float4* src = (const float4*)(cb + (size_t)k * DIM + lane * 8);
        float4 a = src[0], b2 = src[1];
        float vals[8] = {a.x, a.y, a.z, a.w, b2.x, b2.y, b2.z, b2.w};
        float s = 0.f;
        unsigned int h[8];
#pragma unroll
        for (int i = 0; i < 8; ++i) {
            __hip_bfloat16 hb = __float2bfloat16(vals[i]);
            h[i] = __builtin_bit_cast(unsigned short, hb);
            float vb = __bfloat162float(hb);
            s += vb * vb;
        }
        uint4 o;
        o.x = h[0] | (h[1] << 16); o.y = h[2] | (h[3] << 16);
        o.z = h[4] | (h[5] << 16); o.w = h[6] | (h[7] << 16);
        *(uint4*)(cbbf + (size_t)k * DIM + lane * 8) = o;
#pragma unroll
        for (int off = 32; off >= 1; off >>= 1) s += __shfl_down(s, off);
        if (lane == 0) c2[k] = s;
    }
}

// ---------------- pass 1: GEMM + exp on COMPACT rows; S-accum, E bf16 -----------
// Proven 128x128 2-phase structure; MFMA operands swapped (mfma(bv, av, acc) ->
// acc's 4 regs = 4 CONSECUTIVE codebook cols), packed 8B E-stores.
// Rows are compact: valid <=> n < Ntot. Active tiles = ceil(Ntot/128) (~94),
// all fully dense except the last.
// Swapped C/D layout: row (n) = wr + 16*i + (lane&15)
//                     col (k) = wc + 16*j + (lane>>4)*4 + reg
__global__ __launch_bounds__(256, 2) void k_gemm1(
    const unsigned short* __restrict__ zbf, const unsigned short* __restrict__ cbbf,
    const float* __restrict__ z2, const float* __restrict__ c2,
    const int* __restrict__ lengths, const int* __restrict__ stride_p,
    float* __restrict__ Sg, unsigned short* __restrict__ Eg) {
    __shared__ unsigned short As[128 * 64];
    __shared__ unsigned short Bs[128 * 64];
    __shared__ float z2s[128], c2s[128];
    int tid = threadIdx.x;
    int r0 = blockIdx.y * 128, c0 = blockIdx.x * 128;

    int off_, nv_, Ntot;
    row_prefix(lengths, stride_p[0], 0, &off_, &nv_, &Ntot);
    if (r0 >= Ntot) return;                 // beyond compact rows: nothing to do

    if (tid < 128) {
        z2s[tid] = z2[r0 + tid];
        c2s[tid] = c2[c0 + tid];
    }
    __syncthreads();

    int wave = tid >> 6, lane = tid & 63;
    int l15 = lane & 15, l4 = lane >> 4;
    int wr = (wave >> 1) * 64, wc = (wave & 1) * 64;

    int srow = lane >> 3;
    int scg = (lane & 7) ^ srow;
    const unsigned short* ag = zbf + (size_t)(r0 + wave * 32 + srow) * DIM + scg * 8;
    const unsigned short* bg = cbbf + (size_t)(c0 + wave * 32 + srow) * DIM + scg * 8;
    unsigned short* al = As + (wave * 32) * 64;
    unsigned short* bl = Bs + (wave * 32) * 64;

    floatx4 acc[4][4];
    const floatx4 zero = {0.f, 0.f, 0.f, 0.f};
#pragma unroll
    for (int i = 0; i < 4; ++i)
#pragma unroll
        for (int j = 0; j < 4; ++j) acc[i][j] = zero;

    int sw = l15 & 7;

    for (int kc = 0; kc < 8; ++kc) {
#pragma unroll
        for (int q = 0; q < 4; ++q) {
            glds16(ag + (size_t)q * 8 * DIM + kc * 64, al + q * 8 * 64);
            glds16(bg + (size_t)q * 8 * DIM + kc * 64, bl + q * 8 * 64);
        }
        __syncthreads();
#pragma unroll
        for (int ks = 0; ks < 64; ks += 32) {
            int g = (ks >> 3) + l4;
            int pcg = g ^ sw;
            bf16x8 av[4], bv[4];
#pragma unroll
            for (int i = 0; i < 4; ++i)
                av[i] = __builtin_bit_cast(bf16x8,
                    *(const ushortx8*)&As[(wr + 16 * i + l15) * 64 + pcg * 8]);
#pragma unroll
            for (int j = 0; j < 4; ++j)
                bv[j] = __builtin_bit_cast(bf16x8,
                    *(const ushortx8*)&Bs[(wc + 16 * j + l15) * 64 + pcg * 8]);
#pragma unroll
            for (int i = 0; i < 4; ++i)
#pragma unroll
                for (int j = 0; j < 4; ++j)
                    acc[i][j] = __builtin_amdgcn_mfma_f32_16x16x32_bf16(bv[j], av[i], acc[i][j], 0, 0, 0);
        }
        __syncthreads();
    }

    // epilogue: e = exp(SHIFT - sqrt(z2+c2-2*dot)); S += row-sum; E[n][k] packed 8B
    float c2r[4][4];
#pragma unroll
    for (int j = 0; j < 4; ++j)
#pragma unroll
        for (int r = 0; r < 4; ++r)
            c2r[j][r] = c2s[wc + 16 * j + 4 * l4 + r];

#pragma unroll
    for (int i = 0; i < 4; ++i) {
        int rl = wr + 16 * i + l15;
        bool rv = (r0 + rl) < Ntot;
        float z2v = z2s[rl];
        float s = 0.f;
        unsigned short* Ep = Eg + (size_t)(r0 + rl) * NCODES + c0 + wc + l4 * 4;
#pragma unroll
        for (int j = 0; j < 4; ++j) {
            float e[4];
#pragma unroll
            for (int r = 0; r < 4; ++r) {
                float d2 = z2v + c2r[j][r] - 2.0f * acc[i][j][r];
                float d = sqrtf(fmaxf(d2, 1e-12f));
                e[r] = __expf(SHIFTC - d);
                s += e[r];
            }
            if (rv) {
                unsigned h0 = __builtin_bit_cast(unsigned short, __float2bfloat16(e[0]));
                unsigned h1 = __builtin_bit_cast(unsigned short, __float2bfloat16(e[1]));
                unsigned h2 = __builtin_bit_cast(unsigned short, __float2bfloat16(e[2]));
                unsigned h3 = __builtin_bit_cast(unsigned short, __float2bfloat16(e[3]));
                uint2 o;
                o.x = h0 | (h1 << 16);
                o.y = h2 | (h3 << 16);
                *(uint2*)(Ep + 16 * j) = o;
            }
        }
        s += __shfl_xor(s, 16); s += __shfl_xor(s, 32);
        if (l4 == 0 && rv) atomicAdd(&Sg[r0 + rl], s);
    }
}

// ---------------- pass 2: scan compact rows  cdp[slice][k] += E[n][k]/S[n] ------
// Grid (4, 128): 512 blocks = exactly 2/CU. Block (x,y) owns cols x*1024+[0,1024)
// and compact rows {y + 128*j}. Compact rows are valid iff < Ntot, so the valid
// j's are a contiguous prefix -- no ballot/compaction needed. 8-deep MLP.
__global__ __launch_bounds__(256) void k_scan(
    const unsigned short* __restrict__ Eg, const float* __restrict__ Sg,
    const int* __restrict__ lengths, const int* __restrict__ stride_p,
    float* __restrict__ cdp) {
    __shared__ float rs2[RPB];
    int tid = threadIdx.x;
    int y0 = blockIdx.y;                    // 0..127

    int off_, nv_, Ntot;
    row_prefix(lengths, stride_p[0], 0, &off_, &nv_, &Ntot);
    int m = (y0 < Ntot) ? ((Ntot - 1 - y0) / 128 + 1) : 0;
    if (m > RPB) m = RPB;
    if (m == 0) return;

    if (tid < m) rs2[tid] = 1.0f / Sg[y0 + 128 * tid];
    __syncthreads();

    int col0 = blockIdx.x * 1024 + tid * 4;
    const unsigned short* base_e = Eg + col0;
    float acc[4] = {0.f, 0.f, 0.f, 0.f};

#define ACC4(V, RN) do { \
    unsigned int _u[2] = {(V).x, (V).y}; \
    _Pragma("unroll") \
    for (int q = 0; q < 2; ++q) { \
        acc[2 * q]     += (RN) * __builtin_bit_cast(float, _u[q] << 16); \
        acc[2 * q + 1] += (RN) * __builtin_bit_cast(float, _u[q] & 0xffff0000u); \
    } \
} while (0)

#define ROWP(I) (base_e + (size_t)(y0 + 128 * (I)) * NCODES)
    int i = 0;
    for (; i + 8 <= m; i += 8) {
        uint2 v0 = *(const uint2*)ROWP(i);
        uint2 v1 = *(const uint2*)ROWP(i + 1);
        uint2 v2 = *(const uint2*)ROWP(i + 2);
        uint2 v3 = *(const uint2*)ROWP(i + 3);
        uint2 v4 = *(const uint2*)ROWP(i + 4);
        uint2 v5 = *(const uint2*)ROWP(i + 5);
        uint2 v6 = *(const uint2*)ROWP(i + 6);
        uint2 v7 = *(const uint2*)ROWP(i + 7);
        ACC4(v0, rs2[i]);     ACC4(v1, rs2[i + 1]);
        ACC4(v2, rs2[i + 2]); ACC4(v3, rs2[i + 3]);
        ACC4(v4, rs2[i + 4]); ACC4(v5, rs2[i + 5]);
        ACC4(v6, rs2[i + 6]); ACC4(v7, rs2[i + 7]);
    }
    for (; i < m; ++i) {
        uint2 v = *(const uint2*)ROWP(i);
        ACC4(v, rs2[i]);
    }
#undef ROWP
#undef ACC4

    float* outp = cdp + (size_t)(blockIdx.y & (NSLICE - 1)) * NCODES;
#pragma unroll
    for (int t = 0; t < 4; ++t) atomicAdd(&outp[col0 + t], acc[t]);
}

// ---------------- fallback (small ws): two-pass GEMM on compact rows ------------
template <int PASS>
__global__ __launch_bounds__(256, 2) void k_gemm(
    const unsigned short* __restrict__ zbf, const unsigned short* __restrict__ cbbf,
    const float* __restrict__ z2, const float* __restrict__ c2,
    const int* __restrict__ lengths, const int* __restrict__ stride_p,
    float* __restrict__ Sg, float* __restrict__ cd) {
    __shared__ unsigned short Asf[128 * 64];
    __shared__ unsigned short Bsf[128 * 64];
    __shared__ float z2s[128], c2s[128], rs[128];
    int tid = threadIdx.x;
    int r0 = blockIdx.y * 128, c0 = blockIdx.x * 128;
    int off_, nv_, Ntot;
    row_prefix(lengths, stride_p[0], 0, &off_, &nv_, &Ntot);
    if (r0 >= Ntot) return;
    if (tid < 128) {
        z2s[tid] = z2[r0 + tid];
        c2s[tid] = c2[c0 + tid];
        if (PASS == 2) rs[tid] = ((r0 + tid) < Ntot) ? (1.0f / Sg[r0 + tid]) : 0.0f;
    }
    __syncthreads();

    int wave = tid >> 6, lane = tid & 63;
    int l15 = lane & 15, l4 = lane >> 4;
    int wr = (wave >> 1) * 64, wc = (wave & 1) * 64;
    int srow = lane >> 3;
    int scg = (lane & 7) ^ srow;
    const unsigned short* ag = zbf + (size_t)(r0 + wave * 32 + srow) * DIM + scg * 8;
    const unsigned short* bg = cbbf + (size_t)(c0 + wave * 32 + srow) * DIM + scg * 8;
    unsigned short* al = Asf + (wave * 32) * 64;
    unsigned short* bl = Bsf + (wave * 32) * 64;

    floatx4 acc[4][4];
    const floatx4 zero = {0.f, 0.f, 0.f, 0.f};
#pragma unroll
    for (int i = 0; i < 4; ++i)
#pragma unroll
        for (int j = 0; j < 4; ++j) acc[i][j] = zero;
    int sw = l15 & 7;
    for (int kc = 0; kc < 8; ++kc) {
#pragma unroll
        for (int q = 0; q < 4; ++q) {
            glds16(ag + (size_t)q * 8 * DIM + kc * 64, al + q * 8 * 64);
            glds16(bg + (size_t)q * 8 * DIM + kc * 64, bl + q * 8 * 64);
        }
        __syncthreads();
#pragma unroll
        for (int ks = 0; ks < 64; ks += 32) {
            int g = (ks >> 3) + l4;
            int pcg = g ^ sw;
            bf16x8 av[4], bvv[4];
#pragma unroll
            for (int i = 0; i < 4; ++i)
                av[i] = __builtin_bit_cast(bf16x8, *(const ushortx8*)&Asf[(wr + 16 * i + l15) * 64 + pcg * 8]);
#pragma unroll
            for (int j = 0; j < 4; ++j)
                bvv[j] = __builtin_bit_cast(bf16x8, *(const ushortx8*)&Bsf[(wc + 16 * j + l15) * 64 + pcg * 8]);
#pragma unroll
            for (int i = 0; i < 4; ++i)
#pragma unroll
                for (int j = 0; j < 4; ++j)
                    acc[i][j] = __builtin_amdgcn_mfma_f32_16x16x32_bf16(av[i], bvv[j], acc[i][j], 0, 0, 0);
        }
        __syncthreads();
    }
    if (PASS == 1) {
#pragma unroll
        for (int i = 0; i < 4; ++i) {
#pragma unroll
            for (int r = 0; r < 4; ++r) {
                int rl = wr + 16 * i + 4 * l4 + r;
                bool rv = (r0 + rl) < Ntot;
                float z2v = z2s[rl];
                float s = 0.f;
#pragma unroll
                for (int j = 0; j < 4; ++j) {
                    int cl = wc + 16 * j + l15;
                    float d2 = z2v + c2s[cl] - 2.0f * acc[i][j][r];
                    float d = sqrtf(fmaxf(d2, 1e-12f));
                    s += __expf(SHIFTC - d);
                }
                s += __shfl_xor(s, 1); s += __shfl_xor(s, 2);
                s += __shfl_xor(s, 4); s += __shfl_xor(s, 8);
                if (l15 == 0 && rv) atomicAdd(&Sg[r0 + rl], s);
            }
        }
    } else {
#pragma unroll
        for (int j = 0; j < 4; ++j) {
            int cl = wc + 16 * j + l15;
            float c2v = c2s[cl];
            float cs = 0.f;
#pragma unroll
            for (int i = 0; i < 4; ++i) {
#pragma unroll
                for (int r = 0; r < 4; ++r) {
                    int rl = wr + 16 * i + 4 * l4 + r;
                    float d2 = z2s[rl] + c2v - 2.0f * acc[i][j][r];
                    float d = sqrtf(fmaxf(d2, 1e-12f));
                    cs += __expf(SHIFTC - d) * rs[rl];
                }
            }
            cs += __shfl_xor(cs, 16); cs += __shfl_xor(cs, 32);
            if (l4 == 0) atomicAdd(&cd[c0 + cl], cs);
        }
    }
}

// ---------------- finalize (2-stage, 16 blocks each) ----------------------------
__global__ __launch_bounds__(256) void k_red(float* __restrict__ cdp,
                                             float* __restrict__ tot) {
    int k = blockIdx.x * 256 + threadIdx.x;
    float v = 0.f;
#pragma unroll
    for (int s = 0; s < NSLICE; ++s) v += cdp[(size_t)s * NCODES + k];
    cdp[k] = v;
    float t = v;
#pragma unroll
    for (int off = 32; off >= 1; off >>= 1) t += __shfl_down(t, off);
    if ((threadIdx.x & 63) == 0) atomicAdd(tot, t);
}

__global__ __launch_bounds__(256) void k_ent(const float* __restrict__ cdp,
                                             const float* __restrict__ tot,
                                             float* __restrict__ out) {
    int k = blockIdx.x * 256 + threadIdx.x;
    float inv = 1.0f / (tot[0] + 1e-8f);
    float p = cdp[k] * inv;
    float e = p * __logf(p + 1e-8f);
#pragma unroll
    for (int off = 32; off >= 1; off >>= 1) e += __shfl_down(e, off);
    if ((threadIdx.x & 63) == 0)
        atomicAdd(out, e * (1.0f / __logf((float)NCODES)));
}

// ---------------- launcher ----------------
extern "C" void kernel_launch(void* const* d_in, const int* in_sizes, int n_in,
                              void* d_out, int out_size, void* d_ws, size_t ws_size,
                              hipStream_t stream) {
    const float* sf = (const float*)d_in[0];
    const float* cb = (const float*)d_in[1];
    const int* lengths = (const int*)d_in[2];
    const int* stride_p = (const int*)d_in[3];

    float* wsf = (float*)d_ws;
    float* Sg = wsf;                                     // NROWS_PAD
    float* cdp = Sg + NROWS_PAD;                         // NSLICE*NCODES
    float* tot = wsf + NZERO;                            // 1 scalar
    const size_t OFF_Z2 = NZERO2;
    const size_t OFF_C2 = OFF_Z2 + NROWS_PAD;
    const size_t OFF_ZB = (OFF_C2 + NCODES + 3) & ~(size_t)3;  // 16B-align bf16 region
    float* z2 = wsf + OFF_Z2;
    float* c2 = wsf + OFF_C2;
    unsigned short* zbf = (unsigned short*)(wsf + OFF_ZB);     // NROWS_PAD*DIM bf16
    unsigned short* cbbf = zbf + (size_t)NROWS_PAD * DIM;      // NCODES*DIM bf16
    unsigned short* Eg = cbbf + (size_t)NCODES * DIM;          // NROWS_PAD*NCODES bf16

    size_t need = OFF_ZB * 4
                + ((size_t)NROWS_PAD * DIM + (size_t)NCODES * DIM
                 + (size_t)NROWS_PAD * NCODES) * 2;

    k_prep<<<dim3(TBLKS + CBLKS), 256, 0, stream>>>(
        sf, cb, lengths, stride_p, zbf, cbbf, z2, c2, Sg, (float*)d_out);
    if (ws_size >= need) {
        k_gemm1<<<dim3(NBLKX, ROW_TILES), 256, 0, stream>>>(
            zbf, cbbf, z2, c2, lengths, stride_p, Sg, Eg);
        k_scan<<<dim3(4, 128), 256, 0, stream>>>(
            Eg, Sg, lengths, stride_p, cdp);
    } else {
        k_gemm<1><<<dim3(NBLKX, ROW_TILES), 256, 0, stream>>>(zbf, cbbf, z2, c2, lengths, stride_p, Sg, cdp);
        k_gemm<2><<<dim3(NBLKX, ROW_TILES), 256, 0, stream>>>(zbf, cbbf, z2, c2, lengths, stride_p, Sg, cdp);
    }
    k_red<<<dim3(NCODES / 256), 256, 0, stream>>>(cdp, tot);
    k_ent<<<dim3(NCODES / 256), 256, 0, stream>>>(cdp, tot, (float*)d_out);
}

// Round 12
// 203.883 us; speedup vs baseline: 1.0831x; 1.0007x over previous
//
#include <hip/hip_runtime.h>
#include <hip/hip_bf16.h>

// ---------------- problem constants (fixed by setup_inputs) ----------------
#define NUM_B   16
#define DIM     512
#define TT      1500
#define NROWS   (NUM_B * TT)              // 24000
#define NCODES  4096
#define ROW_TILES ((NROWS + 127) / 128)   // 188
#define NROWS_PAD (ROW_TILES * 128)       // 24064
#define NSLICE  8                         // partial cd slices (atomic decontention)
#define SHIFTC  30.0f                     // exp shift: exp(SHIFT-d), cancels in softmax
#define NBLKX   (NCODES / 128)            // 32 col tiles
#define TBLKS   (NUM_B * 47)              // 752 transpose blocks (47 t-tiles of 32)
#define CBLKS   (NCODES / 4)              // 1024 cb blocks
#define NZERO   (NROWS_PAD + NSLICE * NCODES)   // Sg + cdp
#define NZERO2  (NZERO + 1)               // + tot scalar
#define RPB     188                       // max rows per scan block (NROWS_PAD/128)

typedef __bf16 bf16x8 __attribute__((ext_vector_type(8)));
typedef float  floatx4 __attribute__((ext_vector_type(4)));
typedef unsigned short ushortx8 __attribute__((ext_vector_type(8)));

// async global->LDS, 16B per lane; dest = wave-uniform base + lane*16
__device__ __forceinline__ void glds16(const void* g, void* l) {
    __builtin_amdgcn_global_load_lds(
        (__attribute__((address_space(1))) void*)(void*)g,
        (__attribute__((address_space(3))) void*)l, 16, 0, 0);
}

// valid-row count per batch + exclusive prefix (uniform, 16 scalar reads)
__device__ __forceinline__ void row_prefix(const int* __restrict__ lengths,
                                           int stride, int b,
                                           int* off_out, int* nv_out, int* tot_out) {
    int off = 0, nvb = 0, tot = 0;
#pragma unroll
    for (int bb = 0; bb < NUM_B; ++bb) {
        int nv = lengths[bb] / stride;
        if (nv > TT) nv = TT;
        if (bb < b) off += nv;
        if (bb == b) nvb = nv;
        tot += nv;
    }
    *off_out = off; *nv_out = nvb; *tot_out = tot;
}

// ---------------- prep: COMPACTED transpose + z2 + cb + ws zeroing --------------
// Valid rows (t < nv_b) are written to zbf/z2 at compact index off_b + t.
// Transpose blocks whose entire 32-row t-tile is invalid exit before loading
// (~halves transpose traffic for random lengths). Invalid rows never exist in
// the compact arrays; downstream validity is simply n < Ntot.
__global__ __launch_bounds__(256) void k_prep(
    const float* __restrict__ sf, const float* __restrict__ cb,
    const int* __restrict__ lengths, const int* __restrict__ stride_p,
    unsigned short* __restrict__ zbf, unsigned short* __restrict__ cbbf,
    float* __restrict__ z2, float* __restrict__ c2, float* __restrict__ zero0,
    float* __restrict__ outp) {
    int id = blockIdx.x, tid = threadIdx.x;
    if (id < TBLKS) {
        int b = id / 47, t0 = (id % 47) * 32;
        int off, nvb, tot;
        row_prefix(lengths, stride_p[0], b, &off, &nvb, &tot);
        if (t0 >= nvb) return;              // fully-invalid t-tile: nothing to emit

        __shared__ float tile[32][257];
        int tl = tid & 31, dg = tid >> 5;       // phase 1: t lane, d group (8x32)
        int tr = tid >> 3, dgr = tid & 7;       // phase 2: 8 lanes per t-row
        int tg = t0 + tr;
        float ssq = 0.f;
        unsigned short* dst = zbf + (size_t)(off + tg) * DIM;
#pragma unroll
        for (int half = 0; half < 2; ++half) {
            int dbase = half * 256;
            if (half) __syncthreads();          // drain phase-2 reads of prev half
            int t = t0 + tl;
            if (t < TT) {
                const float* src = sf + (size_t)(b * DIM + dbase + dg * 32) * TT + t;
#pragma unroll
                for (int k = 0; k < 32; ++k)
                    tile[tl][dg * 32 + k] = src[(size_t)k * TT];
            }
            __syncthreads();
            if (tg < nvb) {
#pragma unroll
                for (int seg = 0; seg < 4; ++seg) {
                    int d0 = seg * 64 + dgr * 8;
                    unsigned int h[8];
#pragma unroll
                    for (int i2 = 0; i2 < 8; ++i2) {
                        __hip_bfloat16 hb = __float2bfloat16(tile[tr][d0 + i2]);
                        h[i2] = __builtin_bit_cast(unsigned short, hb);
                        float vb = __bfloat162float(hb);
                        ssq += vb * vb;
                    }
                    uint4 o;
                    o.x = h[0] | (h[1] << 16); o.y = h[2] | (h[3] << 16);
                    o.z = h[4] | (h[5] << 16); o.w = h[6] | (h[7] << 16);
                    *(uint4*)(dst + dbase + d0) = o;
                }
            }
        }
        // reduce over the 8 lanes sharing tr (lane bits 0..2)
        ssq += __shfl_xor(ssq, 1); ssq += __shfl_xor(ssq, 2); ssq += __shfl_xor(ssq, 4);
        if (dgr == 0 && tg < nvb) z2[off + tg] = ssq;
    } else {
        int ci = id - TBLKS;
        int gid = ci * 256 + tid;
        if (gid < NZERO2) zero0[gid] = 0.f;     // Sg + cdp + tot
        if (ci == 0 && tid == 0) outp[0] = 1.0f;
        int k = ci * 4 + (tid >> 6);
        int lane = tid & 63;
        const float4* src = (const float4*)(cb + (size_t)k * DIM + lane * 8);
        float4 a = src[0], b2 = src[1];
        float vals[8] = {a.x, a.y, a.z, a.w, b2.x, b2.y, b2.z, b2.w};
        float s = 0.f;
        unsigned int h[8];
#pragma unroll
        for (int i = 0; i < 8; ++i) {
            __hip_bfloat16 hb = __float2bfloat16(vals[i]);
            h[i] = __builtin_bit_cast(unsigned short, hb);
            float vb = __bfloat162float(hb);
            s += vb * vb;
        }
        uint4 o;
        o.x = h[0] | (h[1] << 16); o.y = h[2] | (h[3] << 16);
        o.z = h[4] | (h[5] << 16); o.w = h[6] | (h[7] << 16);
        *(uint4*)(cbbf + (size_t)k * DIM + lane * 8) = o;
#pragma unroll
        for (int off = 32; off >= 1; off >>= 1) s += __shfl_down(s, off);
        if (lane == 0) c2[k] = s;
    }
}

// ---------------- pass 1: GEMM + exp on COMPACT rows; S-accum, E bf16 -----------
// Proven 128x128 2-phase structure; MFMA operands swapped (mfma(bv, av, acc) ->
// acc's 4 regs = 4 CONSECUTIVE codebook cols), packed 8B E-stores.
// Rows are compact: valid <=> n < Ntot. Active tiles = ceil(Ntot/128) (~94),
// all fully dense except the last.
// Swapped C/D layout: row (n) = wr + 16*i + (lane&15)
//                     col (k) = wc + 16*j + (lane>>4)*4 + reg
__global__ __launch_bounds__(256, 2) void k_gemm1(
    const unsigned short* __restrict__ zbf, const unsigned short* __restrict__ cbbf,
    const float* __restrict__ z2, const float* __restrict__ c2,
    const int* __restrict__ lengths, const int* __restrict__ stride_p,
    float* __restrict__ Sg, unsigned short* __restrict__ Eg) {
    __shared__ unsigned short As[128 * 64];
    __shared__ unsigned short Bs[128 * 64];
    __shared__ float z2s[128], c2s[128];
    int tid = threadIdx.x;
    int r0 = blockIdx.y * 128, c0 = blockIdx.x * 128;

    int off_, nv_, Ntot;
    row_prefix(lengths, stride_p[0], 0, &off_, &nv_, &Ntot);
    if (r0 >= Ntot) return;                 // beyond compact rows: nothing to do

    if (tid < 128) {
        z2s[tid] = z2[r0 + tid];
        c2s[tid] = c2[c0 + tid];
    }
    __syncthreads();

    int wave = tid >> 6, lane = tid & 63;
    int l15 = lane & 15, l4 = lane >> 4;
    int wr = (wave >> 1) * 64, wc = (wave & 1) * 64;

    int srow = lane >> 3;
    int scg = (lane & 7) ^ srow;
    const unsigned short* ag = zbf + (size_t)(r0 + wave * 32 + srow) * DIM + scg * 8;
    const unsigned short* bg = cbbf + (size_t)(c0 + wave * 32 + srow) * DIM + scg * 8;
    unsigned short* al = As + (wave * 32) * 64;
    unsigned short* bl = Bs + (wave * 32) * 64;

    floatx4 acc[4][4];
    const floatx4 zero = {0.f, 0.f, 0.f, 0.f};
#pragma unroll
    for (int i = 0; i < 4; ++i)
#pragma unroll
        for (int j = 0; j < 4; ++j) acc[i][j] = zero;

    int sw = l15 & 7;

    for (int kc = 0; kc < 8; ++kc) {
#pragma unroll
        for (int q = 0; q < 4; ++q) {
            glds16(ag + (size_t)q * 8 * DIM + kc * 64, al + q * 8 * 64);
            glds16(bg + (size_t)q * 8 * DIM + kc * 64, bl + q * 8 * 64);
        }
        __syncthreads();
#pragma unroll
        for (int ks = 0; ks < 64; ks += 32) {
            int g = (ks >> 3) + l4;
            int pcg = g ^ sw;
            bf16x8 av[4], bv[4];
#pragma unroll
            for (int i = 0; i < 4; ++i)
                av[i] = __builtin_bit_cast(bf16x8,
                    *(const ushortx8*)&As[(wr + 16 * i + l15) * 64 + pcg * 8]);
#pragma unroll
            for (int j = 0; j < 4; ++j)
                bv[j] = __builtin_bit_cast(bf16x8,
                    *(const ushortx8*)&Bs[(wc + 16 * j + l15) * 64 + pcg * 8]);
#pragma unroll
            for (int i = 0; i < 4; ++i)
#pragma unroll
                for (int j = 0; j < 4; ++j)
                    acc[i][j] = __builtin_amdgcn_mfma_f32_16x16x32_bf16(bv[j], av[i], acc[i][j], 0, 0, 0);
        }
        __syncthreads();
    }

    // epilogue: e = exp(SHIFT - sqrt(z2+c2-2*dot)); S += row-sum; E[n][k] packed 8B
    float c2r[4][4];
#pragma unroll
    for (int j = 0; j < 4; ++j)
#pragma unroll
        for (int r = 0; r < 4; ++r)
            c2r[j][r] = c2s[wc + 16 * j + 4 * l4 + r];

#pragma unroll
    for (int i = 0; i < 4; ++i) {
        int rl = wr + 16 * i + l15;
        bool rv = (r0 + rl) < Ntot;
        float z2v = z2s[rl];
        float s = 0.f;
        unsigned short* Ep = Eg + (size_t)(r0 + rl) * NCODES + c0 + wc + l4 * 4;
#pragma unroll
        for (int j = 0; j < 4; ++j) {
            float e[4];
#pragma unroll
            for (int r = 0; r < 4; ++r) {
                float d2 = z2v + c2r[j][r] - 2.0f * acc[i][j][r];
                float d = sqrtf(fmaxf(d2, 1e-12f));
                e[r] = __expf(SHIFTC - d);
                s += e[r];
            }
            if (rv) {
                unsigned h0 = __builtin_bit_cast(unsigned short, __float2bfloat16(e[0]));
                unsigned h1 = __builtin_bit_cast(unsigned short, __float2bfloat16(e[1]));
                unsigned h2 = __builtin_bit_cast(unsigned short, __float2bfloat16(e[2]));
                unsigned h3 = __builtin_bit_cast(unsigned short, __float2bfloat16(e[3]));
                uint2 o;
                o.x = h0 | (h1 << 16);
                o.y = h2 | (h3 << 16);
                *(uint2*)(Ep + 16 * j) = o;
            }
        }
        s += __shfl_xor(s, 16); s += __shfl_xor(s, 32);
        if (l4 == 0 && rv) atomicAdd(&Sg[r0 + rl], s);
    }
}

// ---------------- pass 2: scan compact rows  cdp[slice][k] += E[n][k]/S[n] ------
// Grid (4, 128): 512 blocks = exactly 2/CU. Block (x,y) owns cols x*1024+[0,1024)
// and compact rows {y + 128*j}. Compact rows are valid iff < Ntot, so the valid
// j's are a contiguous prefix -- no ballot/compaction needed. 8-deep MLP.
__global__ __launch_bounds__(256) void k_scan(
    const unsigned short* __restrict__ Eg, const float* __restrict__ Sg,
    const int* __restrict__ lengths, const int* __restrict__ stride_p,
    float* __restrict__ cdp) {
    __shared__ float rs2[RPB];
    int tid = threadIdx.x;
    int y0 = blockIdx.y;                    // 0..127

    int off_, nv_, Ntot;
    row_prefix(lengths, stride_p[0], 0, &off_, &nv_, &Ntot);
    int m = (y0 < Ntot) ? ((Ntot - 1 - y0) / 128 + 1) : 0;
    if (m > RPB) m = RPB;
    if (m == 0) return;

    if (tid < m) rs2[tid] = 1.0f / Sg[y0 + 128 * tid];
    __syncthreads();

    int col0 = blockIdx.x * 1024 + tid * 4;
    const unsigned short* base_e = Eg + col0;
    float acc[4] = {0.f, 0.f, 0.f, 0.f};

#define ACC4(V, RN) do { \
    unsigned int _u[2] = {(V).x, (V).y}; \
    _Pragma("unroll") \
    for (int q = 0; q < 2; ++q) { \
        acc[2 * q]     += (RN) * __builtin_bit_cast(float, _u[q] << 16); \
        acc[2 * q + 1] += (RN) * __builtin_bit_cast(float, _u[q] & 0xffff0000u); \
    } \
} while (0)

#define ROWP(I) (base_e + (size_t)(y0 + 128 * (I)) * NCODES)
    int i = 0;
    for (; i + 8 <= m; i += 8) {
        uint2 v0 = *(const uint2*)ROWP(i);
        uint2 v1 = *(const uint2*)ROWP(i + 1);
        uint2 v2 = *(const uint2*)ROWP(i + 2);
        uint2 v3 = *(const uint2*)ROWP(i + 3);
        uint2 v4 = *(const uint2*)ROWP(i + 4);
        uint2 v5 = *(const uint2*)ROWP(i + 5);
        uint2 v6 = *(const uint2*)ROWP(i + 6);
        uint2 v7 = *(const uint2*)ROWP(i + 7);
        ACC4(v0, rs2[i]);     ACC4(v1, rs2[i + 1]);
        ACC4(v2, rs2[i + 2]); ACC4(v3, rs2[i + 3]);
        ACC4(v4, rs2[i + 4]); ACC4(v5, rs2[i + 5]);
        ACC4(v6, rs2[i + 6]); ACC4(v7, rs2[i + 7]);
    }
    for (; i < m; ++i) {
        uint2 v = *(const uint2*)ROWP(i);
        ACC4(v, rs2[i]);
    }
#undef ROWP
#undef ACC4

    float* outp = cdp + (size_t)(blockIdx.y & (NSLICE - 1)) * NCODES;
#pragma unroll
    for (int t = 0; t < 4; ++t) atomicAdd(&outp[col0 + t], acc[t]);
}

// ---------------- fallback (small ws): two-pass GEMM on compact rows ------------
template <int PASS>
__global__ __launch_bounds__(256, 2) void k_gemm(
    const unsigned short* __restrict__ zbf, const unsigned short* __restrict__ cbbf,
    const float* __restrict__ z2, const float* __restrict__ c2,
    const int* __restrict__ lengths, const int* __restrict__ stride_p,
    float* __restrict__ Sg, float* __restrict__ cd) {
    __shared__ unsigned short Asf[128 * 64];
    __shared__ unsigned short Bsf[128 * 64];
    __shared__ float z2s[128], c2s[128], rs[128];
    int tid = threadIdx.x;
    int r0 = blockIdx.y * 128, c0 = blockIdx.x * 128;
    int off_, nv_, Ntot;
    row_prefix(lengths, stride_p[0], 0, &off_, &nv_, &Ntot);
    if (r0 >= Ntot) return;
    if (tid < 128) {
        z2s[tid] = z2[r0 + tid];
        c2s[tid] = c2[c0 + tid];
        if (PASS == 2) rs[tid] = ((r0 + tid) < Ntot) ? (1.0f / Sg[r0 + tid]) : 0.0f;
    }
    __syncthreads();

    int wave = tid >> 6, lane = tid & 63;
    int l15 = lane & 15, l4 = lane >> 4;
    int wr = (wave >> 1) * 64, wc = (wave & 1) * 64;
    int srow = lane >> 3;
    int scg = (lane & 7) ^ srow;
    const unsigned short* ag = zbf + (size_t)(r0 + wave * 32 + srow) * DIM + scg * 8;
    const unsigned short* bg = cbbf + (size_t)(c0 + wave * 32 + srow) * DIM + scg * 8;
    unsigned short* al = Asf + (wave * 32) * 64;
    unsigned short* bl = Bsf + (wave * 32) * 64;

    floatx4 acc[4][4];
    const floatx4 zero = {0.f, 0.f, 0.f, 0.f};
#pragma unroll
    for (int i = 0; i < 4; ++i)
#pragma unroll
        for (int j = 0; j < 4; ++j) acc[i][j] = zero;
    int sw = l15 & 7;
    for (int kc = 0; kc < 8; ++kc) {
#pragma unroll
        for (int q = 0; q < 4; ++q) {
            glds16(ag + (size_t)q * 8 * DIM + kc * 64, al + q * 8 * 64);
            glds16(bg + (size_t)q * 8 * DIM + kc * 64, bl + q * 8 * 64);
        }
        __syncthreads();
#pragma unroll
        for (int ks = 0; ks < 64; ks += 32) {
            int g = (ks >> 3) + l4;
            int pcg = g ^ sw;
            bf16x8 av[4], bvv[4];
#pragma unroll
            for (int i = 0; i < 4; ++i)
                av[i] = __builtin_bit_cast(bf16x8, *(const ushortx8*)&Asf[(wr + 16 * i + l15) * 64 + pcg * 8]);
#pragma unroll
            for (int j = 0; j < 4; ++j)
                bvv[j] = __builtin_bit_cast(bf16x8, *(const ushortx8*)&Bsf[(wc + 16 * j + l15) * 64 + pcg * 8]);
#pragma unroll
            for (int i = 0; i < 4; ++i)
#pragma unroll
                for (int j = 0; j < 4; ++j)
                    acc[i][j] = __builtin_amdgcn_mfma_f32_16x16x32_bf16(av[i], bvv[j], acc[i][j], 0, 0, 0);
        }
        __syncthreads();
    }
    if (PASS == 1) {
#pragma unroll
        for (int i = 0; i < 4; ++i) {
#pragma unroll
            for (int r = 0; r < 4; ++r) {
                int rl = wr + 16 * i + 4 * l4 + r;
                bool rv = (r0 + rl) < Ntot;
                float z2v = z2s[rl];
                float s = 0.f;
#pragma unroll
                for (int j = 0; j < 4; ++j) {
                    int cl = wc + 16 * j + l15;
                    float d2 = z2v + c2s[cl] - 2.0f * acc[i][j][r];
                    float d = sqrtf(fmaxf(d2, 1e-12f));
                    s += __expf(SHIFTC - d);
                }
                s += __shfl_xor(s, 1); s += __shfl_xor(s, 2);
                s += __shfl_xor(s, 4); s += __shfl_xor(s, 8);
                if (l15 == 0 && rv) atomicAdd(&Sg[r0 + rl], s);
            }
        }
    } else {
#pragma unroll
        for (int j = 0; j < 4; ++j) {
            int cl = wc + 16 * j + l15;
            float c2v = c2s[cl];
            float cs = 0.f;
#pragma unroll
            for (int i = 0; i < 4; ++i) {
#pragma unroll
                for (int r = 0; r < 4; ++r) {
                    int rl = wr + 16 * i + 4 * l4 + r;
                    float d2 = z2s[rl] + c2v - 2.0f * acc[i][j][r];
                    float d = sqrtf(fmaxf(d2, 1e-12f));
                    cs += __expf(SHIFTC - d) * rs[rl];
                }
            }
            cs += __shfl_xor(cs, 16); cs += __shfl_xor(cs, 32);
            if (l4 == 0) atomicAdd(&cd[c0 + cl], cs);
        }
    }
}

// ---------------- finalize (2-stage, 16 blocks each) ----------------------------
__global__ __launch_bounds__(256) void k_red(float* __restrict__ cdp,
                                             float* __restrict__ tot) {
    int k = blockIdx.x * 256 + threadIdx.x;
    float v = 0.f;
#pragma unroll
    for (int s = 0; s < NSLICE; ++s) v += cdp[(size_t)s * NCODES + k];
    cdp[k] = v;
    float t = v;
#pragma unroll
    for (int off = 32; off >= 1; off >>= 1) t += __shfl_down(t, off);
    if ((threadIdx.x & 63) == 0) atomicAdd(tot, t);
}

__global__ __launch_bounds__(256) void k_ent(const float* __restrict__ cdp,
                                             const float* __restrict__ tot,
                                             float* __restrict__ out) {
    int k = blockIdx.x * 256 + threadIdx.x;
    float inv = 1.0f / (tot[0] + 1e-8f);
    float p = cdp[k] * inv;
    float e = p * __logf(p + 1e-8f);
#pragma unroll
    for (int off = 32; off >= 1; off >>= 1) e += __shfl_down(e, off);
    if ((threadIdx.x & 63) == 0)
        atomicAdd(out, e * (1.0f / __logf((float)NCODES)));
}

// ---------------- launcher ----------------
extern "C" void kernel_launch(void* const* d_in, const int* in_sizes, int n_in,
                              void* d_out, int out_size, void* d_ws, size_t ws_size,
                              hipStream_t stream) {
    const float* sf = (const float*)d_in[0];
    const float* cb = (const float*)d_in[1];
    const int* lengths = (const int*)d_in[2];
    const int* stride_p = (const int*)d_in[3];

    float* wsf = (float*)d_ws;
    float* Sg = wsf;                                     // NROWS_PAD
    float* cdp = Sg + NROWS_PAD;                         // NSLICE*NCODES
    float* tot = wsf + NZERO;                            // 1 scalar
    const size_t OFF_Z2 = NZERO2;
    const size_t OFF_C2 = OFF_Z2 + NROWS_PAD;
    const size_t OFF_ZB = (OFF_C2 + NCODES + 3) & ~(size_t)3;  // 16B-align bf16 region
    float* z2 = wsf + OFF_Z2;
    float* c2 = wsf + OFF_C2;
    unsigned short* zbf = (unsigned short*)(wsf + OFF_ZB);     // NROWS_PAD*DIM bf16
    unsigned short* cbbf = zbf + (size_t)NROWS_PAD * DIM;      // NCODES*DIM bf16
    unsigned short* Eg = cbbf + (size_t)NCODES * DIM;          // NROWS_PAD*NCODES bf16

    size_t need = OFF_ZB * 4
                + ((size_t)NROWS_PAD * DIM + (size_t)NCODES * DIM
                 + (size_t)NROWS_PAD * NCODES) * 2;

    k_prep<<<dim3(TBLKS + CBLKS), 256, 0, stream>>>(
        sf, cb, lengths, stride_p, zbf, cbbf, z2, c2, Sg, (float*)d_out);
    if (ws_size >= need) {
        k_gemm1<<<dim3(NBLKX, ROW_TILES), 256, 0, stream>>>(
            zbf, cbbf, z2, c2, lengths, stride_p, Sg, Eg);
        k_scan<<<dim3(4, 128), 256, 0, stream>>>(
            Eg, Sg, lengths, stride_p, cdp);
    } else {
        k_gemm<1><<<dim3(NBLKX, ROW_TILES), 256, 0, stream>>>(zbf, cbbf, z2, c2, lengths, stride_p, Sg, cdp);
        k_gemm<2><<<dim3(NBLKX, ROW_TILES), 256, 0, stream>>>(zbf, cbbf, z2, c2, lengths, stride_p, Sg, cdp);
    }
    k_red<<<dim3(NCODES / 256), 256, 0, stream>>>(cdp, tot);
    k_ent<<<dim3(NCODES / 256), 256, 0, stream>>>(cdp, tot, (float*)d_out);
}